// Round 3
// baseline (439.165 us; speedup 1.0000x reference)
//
#include <hip/hip_runtime.h>

// LocallyConnected2D: out[b,p,f] = sum_k x_patch[b,p,k] * kernel[p,k,f] + bias[p,f]
// B=16, H=W=64, C=32, KH=KW=3, OH=OW=62, P=3844, F=64, fp32.
//
// Memory-bound on the 283 MB weight stream; weights are read exactly once
// (all 16 batches accumulate in registers). R2: R0 structure (float4
// weight loads, 16B/lane) + K-split-2 inside each wave: lanes 0-15 of a
// 32-lane group do channels 0-15, lanes 16-31 do channels 16-31, reduced
// at the end with __shfl_xor(.,16). Doubles waves (961 -> 1922) for
// latency hiding at zero extra weight traffic.
// NOTE (R1 lesson): do NOT make x addresses provably wave-uniform
// (readfirstlane) -> compiler scalarizes to s_load + lgkmcnt(0) drains
// (VGPR=20/SGPR=112, 525 GB/s). Keep x as per-lane VMEM broadcast loads.

namespace {
constexpr int Hc = 64, Wc = 64, Cc = 32;
constexpr int OWc = 62;
constexpr int Pc = 62 * 62;      // 3844
constexpr int Fc = 64;
constexpr int KFc = 288 * 64;    // K*F per position
constexpr int XSTRIDE = Hc * Wc * Cc;  // per-batch x stride (floats)
constexpr int PPB = 8;           // p's per 256-thread block (one per 32-lane group)
}

__global__ __launch_bounds__(256, 2)
void lc2d(const float* __restrict__ x, const float* __restrict__ kern,
          const float* __restrict__ bias, float* __restrict__ out)
{
    const int t    = threadIdx.x;
    const int fq   = t & 15;           // f-quad within p
    const int f0   = fq << 2;
    const int kh2  = (t >> 4) & 1;     // which channel-half (k-split)
    const int psub = t >> 5;
    const int p    = blockIdx.x * PPB + psub;
    if (p >= Pc) return;
    const int oh = p / OWc;
    const int ow = p - oh * OWc;

    const int c0 = kh2 << 4;           // starting channel: 0 or 16
    const float* kbase = kern + (size_t)p * KFc + f0;

    float4 acc[16];
    const float4 bv = *(const float4*)(bias + (size_t)p * Fc + f0);
    const float4 zv = make_float4(0.f, 0.f, 0.f, 0.f);
    #pragma unroll
    for (int b = 0; b < 16; ++b) acc[b] = (kh2 == 0) ? bv : zv;

    #pragma unroll
    for (int kh = 0; kh < 3; ++kh) {
      #pragma unroll
      for (int kw = 0; kw < 3; ++kw) {
        // x[b, oh+kh, ow+kw, c0..c0+16) — per-lane broadcast within 16-lane group
        const float* xb = x + ((size_t)(oh + kh) * Wc + (ow + kw)) * Cc + c0;
        // kernel[p, k, f], k = kh*96 + kw*32 + c
        const float* kk = kbase + (size_t)(kh * 96 + kw * 32 + c0) * Fc;
        #pragma unroll
        for (int c4 = 0; c4 < 4; ++c4) {
          const float4 kv0 = *(const float4*)(kk + (c4 * 4 + 0) * Fc);
          const float4 kv1 = *(const float4*)(kk + (c4 * 4 + 1) * Fc);
          const float4 kv2 = *(const float4*)(kk + (c4 * 4 + 2) * Fc);
          const float4 kv3 = *(const float4*)(kk + (c4 * 4 + 3) * Fc);
          #pragma unroll
          for (int b = 0; b < 16; ++b) {
            const float4 xv = *(const float4*)(xb + (size_t)b * XSTRIDE + c4 * 4);
            acc[b].x = fmaf(xv.x, kv0.x, fmaf(xv.y, kv1.x, fmaf(xv.z, kv2.x, fmaf(xv.w, kv3.x, acc[b].x))));
            acc[b].y = fmaf(xv.x, kv0.y, fmaf(xv.y, kv1.y, fmaf(xv.z, kv2.y, fmaf(xv.w, kv3.y, acc[b].y))));
            acc[b].z = fmaf(xv.x, kv0.z, fmaf(xv.y, kv1.z, fmaf(xv.z, kv2.z, fmaf(xv.w, kv3.z, acc[b].z))));
            acc[b].w = fmaf(xv.x, kv0.w, fmaf(xv.y, kv1.w, fmaf(xv.z, kv2.w, fmaf(xv.w, kv3.w, acc[b].w))));
          }
        }
      }
    }

    // Reduce the two channel-halves: partner lane = lane ^ 16.
    #pragma unroll
    for (int b = 0; b < 16; ++b) {
        acc[b].x += __shfl_xor(acc[b].x, 16);
        acc[b].y += __shfl_xor(acc[b].y, 16);
        acc[b].z += __shfl_xor(acc[b].z, 16);
        acc[b].w += __shfl_xor(acc[b].w, 16);
    }

    // Each half stores 8 of the 16 batches.
    const int bbase = kh2 << 3;
    #pragma unroll
    for (int bb = 0; bb < 8; ++bb) {
        const int b = bbase + bb;
        *(float4*)(out + ((size_t)b * Pc + p) * Fc + f0) = acc[b];
    }
}

extern "C" void kernel_launch(void* const* d_in, const int* in_sizes, int n_in,
                              void* d_out, int out_size, void* d_ws, size_t ws_size,
                              hipStream_t stream)
{
    const float* x    = (const float*)d_in[0];
    const float* kern = (const float*)d_in[1];
    const float* bias = (const float*)d_in[2];
    float* out = (float*)d_out;
    dim3 grid((Pc + PPB - 1) / PPB);   // 481
    lc2d<<<grid, 256, 0, stream>>>(x, kern, bias, out);
}

// Round 4
// 81.065 us; speedup vs baseline: 5.4174x; 5.4174x over previous
//
#include <hip/hip_runtime.h>

// LocallyConnected2D: out[b,p,f] = sum_k x_patch[b,p,k] * kernel[p,k,f] + bias[p,f]
// B=16, H=W=64, C=32, KH=KW=3, OH=OW=62, P=3844, F=64, fp32.
//
// Memory-bound on the 283 MB weight stream (read exactly once: all 16
// batches accumulate in registers, 16 f-lanes per p).
// R3 change vs R0: stage the block's x slab in LDS so weight loads are the
// ONLY vmcnt stream. vmcnt is an in-order FIFO: in R0, waiting on an x load
// (L2) forced draining all earlier weight loads (HBM, ~900cy), killing the
// prefetch pipeline. x reads now come from LDS (lgkmcnt, ~12cy tput).
// LDS layout padded to 36 floats/col-stride: the 4 p's within a wave read
// 4 consecutive cols -> banks 4 apart (conflict-free); 16 f-lanes per p
// read the same address (broadcast, free).
// Lessons: R1 = don't let x addrs become provably wave-uniform (s_load +
// lgkmcnt(0) drains). R2 = don't cap VGPRs below acc[16]*float4 (spill ->
// 911 MB scratch writes).

namespace {
constexpr int Hc = 64, Wc = 64, Cc = 32;
constexpr int OWc = 62, OHc = 62;
constexpr int Pc = 62 * 62;      // 3844
constexpr int Fc = 64;
constexpr int KFc = 288 * 64;    // K*F per position
constexpr int TW = 16;           // ow-tile width (p's per block)
constexpr int COLS = TW + 2;     // 18 staged cols
constexpr int CPAD = 36;         // padded per-col float count (bank stagger)
}

__global__ __launch_bounds__(256, 1)
void lc2d(const float* __restrict__ x, const float* __restrict__ kern,
          const float* __restrict__ bias, float* __restrict__ out)
{
    __shared__ float xs[16][3][COLS][CPAD];   // 124,416 B

    const int t  = threadIdx.x;
    const int oh = blockIdx.y;
    const int w0 = blockIdx.x * TW;

    // ---- stage x slab: x[b, oh..oh+2, w0..w0+17, 0..32) ----
    // 16*3*18*8 = 6912 float4 chunks, 27 per thread. Edge tiles clamp the
    // global col (duplicate data into never-read cols; keeps decode static).
    #pragma unroll
    for (int i = 0; i < 27; ++i) {
        const int ch  = t + i * 256;
        const int c4  = ch & 7;
        const int col = (ch >> 3) % COLS;
        const int r   = ((ch >> 3) / COLS) % 3;
        const int b   = (ch >> 3) / (COLS * 3);
        const int gcol = min(w0 + col, Wc - 1);
        const float4 v = *(const float4*)(x + ((size_t)((b * Hc + oh + r) * Wc + gcol)) * Cc + c4 * 4);
        *(float4*)&xs[b][r][col][c4 * 4] = v;
    }
    __syncthreads();

    const int fq   = t & 15;
    const int f0   = fq << 2;
    const int psub = t >> 4;
    const int ow   = w0 + psub;
    if (ow >= OWc) return;          // after the only barrier: safe
    const int p = oh * OWc + ow;

    const float* kbase = kern + (size_t)p * KFc + f0;

    float4 acc[16];
    const float4 bv = *(const float4*)(bias + (size_t)p * Fc + f0);
    #pragma unroll
    for (int b = 0; b < 16; ++b) acc[b] = bv;

    #pragma unroll
    for (int kh = 0; kh < 3; ++kh) {
      #pragma unroll
      for (int kw = 0; kw < 3; ++kw) {
        const float* kk = kbase + (size_t)((kh * 3 + kw) * 32) * Fc;
        const int col = psub + kw;
        #pragma unroll 4
        for (int c4 = 0; c4 < 8; ++c4) {
          const float4 kv0 = *(const float4*)(kk + (c4 * 4 + 0) * Fc);
          const float4 kv1 = *(const float4*)(kk + (c4 * 4 + 1) * Fc);
          const float4 kv2 = *(const float4*)(kk + (c4 * 4 + 2) * Fc);
          const float4 kv3 = *(const float4*)(kk + (c4 * 4 + 3) * Fc);
          #pragma unroll
          for (int b = 0; b < 16; ++b) {
            const float4 xv = *(const float4*)&xs[b][kh][col][c4 * 4];
            acc[b].x = fmaf(xv.x, kv0.x, fmaf(xv.y, kv1.x, fmaf(xv.z, kv2.x, fmaf(xv.w, kv3.x, acc[b].x))));
            acc[b].y = fmaf(xv.x, kv0.y, fmaf(xv.y, kv1.y, fmaf(xv.z, kv2.y, fmaf(xv.w, kv3.y, acc[b].y))));
            acc[b].z = fmaf(xv.x, kv0.z, fmaf(xv.y, kv1.z, fmaf(xv.z, kv2.z, fmaf(xv.w, kv3.z, acc[b].z))));
            acc[b].w = fmaf(xv.x, kv0.w, fmaf(xv.y, kv1.w, fmaf(xv.z, kv2.w, fmaf(xv.w, kv3.w, acc[b].w))));
          }
        }
      }
    }

    #pragma unroll
    for (int b = 0; b < 16; ++b)
        *(float4*)(out + ((size_t)b * Pc + p) * Fc + f0) = acc[b];
}

extern "C" void kernel_launch(void* const* d_in, const int* in_sizes, int n_in,
                              void* d_out, int out_size, void* d_ws, size_t ws_size,
                              hipStream_t stream)
{
    const float* x    = (const float*)d_in[0];
    const float* kern = (const float*)d_in[1];
    const float* bias = (const float*)d_in[2];
    float* out = (float*)d_out;
    dim3 grid((OWc + TW - 1) / TW, OHc);   // 4 x 62 = 248 blocks
    lc2d<<<grid, 256, 0, stream>>>(x, kern, bias, out);
}